// Round 8
// baseline (191.964 us; speedup 1.0000x reference)
//
#include <hip/hip_runtime.h>

// Prompt-phase causal GQA flash attention + fused score-sum, MI355X gfx950.
// B=2 S=2048 H=16 Hk=4 D=128; bf16 MFMA 16x16x32, fp32 accumulate.
//
// R11: in-register P via permuted-V (algebraic identity). R4-R10 showed fa2
// invariant (72-84us) to waves/traffic/schedule/barrier-count -> the bound
// is the per-substep serial chain. Its one constant element: the P LDS
// round-trip (4 ds_write + lgkmcnt(0) + ds_read_b128, ~200cyc serial,
// fingerprinted by SQ_LDS_BANK_CONFLICT == 1622016 in EVERY round).
// MFMA contraction is permutation-invariant in k: prep stores V's k-rows
// permuted by pi(qd*8+e) = qd*4 + (e&3) + 16*(e>>2), so the pack2bf words
// each lane already holds ARE the PV B-operand fragment. Round-trip, ldsP,
// and the lgkmcnt(0) all deleted. QK 4-deep MFMA chains split into 2+2.
// Shell = R10 (64-col intervals, V from global, grid 1024, 4 waves x 16q).

#define BB 2
#define SS 2048
#define NH 16
#define NKV 4
#define DD 128
#define TILE_SH 4096  // shorts per 8KB (32k x 128d bf16) tile

typedef __attribute__((ext_vector_type(8))) short bf16x8;
typedef __attribute__((ext_vector_type(4))) float f32x4;

// softmax scale folded with log2(e): probs = exp2(s*SCL)
constexpr float SCL = 0.08838834764831845f * 1.4426950408889634f;

__device__ __forceinline__ short f2bf(float f) {
  union { float f; unsigned u; } v; v.f = f;
  unsigned r = v.u + 0x7FFFu + ((v.u >> 16) & 1u);  // RNE
  return (short)(r >> 16);
}

// packed bf16 truncation: low short = trunc_bf16(a), high short = trunc_bf16(b)
__device__ __forceinline__ unsigned pack2bf(float a, float b) {
  union { float f; unsigned u; } x, y; x.f = a; y.f = b;
  return __builtin_amdgcn_perm(y.u, x.u, 0x07060302);
}

__device__ __forceinline__ void gl_lds16(const void* g, void* l) {
  __builtin_amdgcn_global_load_lds(
      (const __attribute__((address_space(1))) unsigned*)g,
      (__attribute__((address_space(3))) unsigned*)l, 16, 0, 0);
}

// ---------------------------------------------------------------------------
// prep: K -> Kb [b][hk][kt32][ch=d/8][k0..31] (bf16x8 chunks along d)
//       V -> Vb [b][hk][kt32][kc][d0..127] with k-rows PERMUTED:
//       element e of chunk kc holds V[k0 + kc*4 + (e&3) + 16*(e>>2)][d],
//       matching the in-register P fragment's k-order in fa2.
// ---------------------------------------------------------------------------
__global__ void prep(const float* __restrict__ K, const float* __restrict__ V,
                     short* __restrict__ Kb, short* __restrict__ Vb) {
  const int p = blockIdx.x;
  const int b = p >> 8, hk = (p >> 6) & 3, kt = p & 63;
  const int tid = threadIdx.x;
  const int k0 = kt * 32;
  short* kb = Kb + ((size_t)((b * 4 + hk) * 64 + kt)) * TILE_SH;
  short* vb = Vb + ((size_t)((b * 4 + hk) * 64 + kt)) * TILE_SH;
  {
    const int k = tid & 31, chb = tid >> 5;  // chb 0..7
    const float* src = K + ((size_t)(b * SS + k0 + k) * NKV + hk) * DD;
#pragma unroll
    for (int i = 0; i < 2; ++i) {
      const int ch = chb + i * 8;
      const float* s = src + ch * 8;
      float4 f0 = *(const float4*)s;
      float4 f1 = *(const float4*)(s + 4);
      bf16x8 t;
      t[0] = f2bf(f0.x); t[1] = f2bf(f0.y); t[2] = f2bf(f0.z); t[3] = f2bf(f0.w);
      t[4] = f2bf(f1.x); t[5] = f2bf(f1.y); t[6] = f2bf(f1.z); t[7] = f2bf(f1.w);
      *(bf16x8*)(kb + (ch * 32 + k) * 8) = t;
    }
  }
  {
    const int d = tid & 127, kcb = tid >> 7;  // 0..1
#pragma unroll
    for (int i = 0; i < 2; ++i) {
      const int kc = kcb + i * 2;
      // permuted gather: e -> k offset kc*4 + (e&3) + 16*(e>>2)
      const float* s = V + ((size_t)(b * SS + k0 + kc * 4) * NKV + hk) * DD + d;
      bf16x8 t;
#pragma unroll
      for (int e = 0; e < 8; ++e)
        t[e] = f2bf(s[(size_t)((e & 3) + 16 * (e >> 2)) * (NKV * DD)]);
      *(bf16x8*)(vb + (kc * 128 + d) * 8) = t;
    }
  }
}

// ---------------------------------------------------------------------------
// fa2: grid 1024, 256 threads (4 waves x 16 q-rows), one q-tile per block.
// Transposed pipeline: St = K Q^T, O^T = V^T P^T; lane owns one q-row.
// P stays in registers: packed bf16 words feed PV directly (V k-permuted).
// Interval = 64 kcols (2 prep-tiles), K dbuf in LDS, V from global.
// R4 schedule: i = g*256 + bh*8 + jp; qt(g,jp) = {jp, 31-jp, 8+jp, 23-jp}.
// ---------------------------------------------------------------------------
__global__ __launch_bounds__(256, 4) void fa2(
    const float* __restrict__ Q, const short* __restrict__ Kb,
    const short* __restrict__ Vb, float* __restrict__ Out,
    float* __restrict__ wsl) {
  __shared__ bf16x8 kv[2][1024];  // [buf][K tile even 0..511 | K tile odd 512..1023]

  const int tid = threadIdx.x;
  const int w = tid >> 6, lane = tid & 63;
  const int c = lane & 15, qd = lane >> 4;

  const int i = blockIdx.x;
  const int g = i >> 8, cc = i & 255;
  const int bh = cc >> 3, jp = cc & 7;
  const int qt = (g == 0) ? jp : (g == 1) ? 31 - jp : (g == 2) ? 8 + jp : 23 - jp;
  const int b = bh >> 4, h = bh & 15, hk = h >> 2;

  const char* KT = (const char*)(Kb + ((size_t)(b * 4 + hk)) * 64 * TILE_SH);
  const char* VT = (const char*)(Vb + ((size_t)(b * 4 + hk)) * 64 * TILE_SH);

  // stage one 64-col interval (two 8KB K tiles, contiguous 16KB)
  auto stage = [&](int iv, int bi) {
    const char* sk = KT + (size_t)iv * 16384 + w * 4096 + lane * 16;
    char* dk = (char*)kv[bi] + w * 4096;
#pragma unroll
    for (int t = 0; t < 4; ++t) gl_lds16(sk + t * 1024, dk + t * 1024);
  };

  stage(0, 0);

  // Q fragments, pre-scaled by SCL: lane owns q-row qt*64 + w*16 + c
  const float* qrow = Q + ((size_t)(b * SS + qt * 64 + w * 16 + c) * NH + h) * DD;
  bf16x8 qf[4];
#pragma unroll
  for (int ks = 0; ks < 4; ++ks) {
    const float* p = qrow + ks * 32 + qd * 8;
    float4 f0 = *(const float4*)p;
    float4 f1 = *(const float4*)(p + 4);
    bf16x8 tq;
    tq[0] = f2bf(f0.x * SCL); tq[1] = f2bf(f0.y * SCL);
    tq[2] = f2bf(f0.z * SCL); tq[3] = f2bf(f0.w * SCL);
    tq[4] = f2bf(f1.x * SCL); tq[5] = f2bf(f1.y * SCL);
    tq[6] = f2bf(f1.z * SCL); tq[7] = f2bf(f1.w * SCL);
    qf[ks] = tq;
  }

  f32x4 o[8];  // O^T frags: d = dt*16+qd*4+r, q = c
#pragma unroll
  for (int dt = 0; dt < 8; ++dt) { o[dt][0] = 0.f; o[dt][1] = 0.f; o[dt][2] = 0.f; o[dt][3] = 0.f; }
  float l_part = 0.f;

  const int niv = qt + 1;  // 64-col intervals; covers tiles 0..2qt+1

  // QK sub-step on one 8KB K tile + softmax + in-register pack -> B-operand
  // frag (k-order matches the permuted V layout; no LDS round-trip).
  auto qkp = [&](const bf16x8* bKt, int kt) -> bf16x8 {
    f32x4 s0a = {0.f, 0.f, 0.f, 0.f}, s0b = {0.f, 0.f, 0.f, 0.f};
    f32x4 s1a = {0.f, 0.f, 0.f, 0.f}, s1b = {0.f, 0.f, 0.f, 0.f};
    // split 4-deep accumulate chains into 2+2 (shorter dependency)
#pragma unroll
    for (int ks = 0; ks < 2; ++ks) {
      const int chz = (ks * 4 + qd) * 32;
      bf16x8 a0 = bKt[chz + c];
      bf16x8 a1 = bKt[chz + 16 + c];
      s0a = __builtin_amdgcn_mfma_f32_16x16x32_bf16(a0, qf[ks], s0a, 0, 0, 0);
      s1a = __builtin_amdgcn_mfma_f32_16x16x32_bf16(a1, qf[ks], s1a, 0, 0, 0);
    }
#pragma unroll
    for (int ks = 2; ks < 4; ++ks) {
      const int chz = (ks * 4 + qd) * 32;
      bf16x8 a0 = bKt[chz + c];
      bf16x8 a1 = bKt[chz + 16 + c];
      s0b = __builtin_amdgcn_mfma_f32_16x16x32_bf16(a0, qf[ks], s0b, 0, 0, 0);
      s1b = __builtin_amdgcn_mfma_f32_16x16x32_bf16(a1, qf[ks], s1b, 0, 0, 0);
    }
    float pr[8];
#pragma unroll
    for (int r = 0; r < 4; ++r) {
      pr[r] = exp2f(s0a[r] + s0b[r]);
      pr[4 + r] = exp2f(s1a[r] + s1b[r]);
    }
    const int koff = kt * 32 - qt * 64;
    if (koff >= 0) {  // diagonal tiles only
      const int qrl = w * 16 + c;
#pragma unroll
      for (int mt = 0; mt < 2; ++mt)
#pragma unroll
        for (int r = 0; r < 4; ++r)
          if (koff + mt * 16 + qd * 4 + r > qrl) pr[mt * 4 + r] = 0.f;
    }
#pragma unroll
    for (int x = 0; x < 8; ++x) l_part += pr[x];

    // in-register B-operand: element e holds P[k = qd*4 + (e&3) + 16*(e>>2)],
    // exactly the k-order baked into Vb by prep.
    union { unsigned u[4]; bf16x8 v; } pk;
    pk.u[0] = pack2bf(pr[0], pr[1]);
    pk.u[1] = pack2bf(pr[2], pr[3]);
    pk.u[2] = pack2bf(pr[4], pr[5]);
    pk.u[3] = pack2bf(pr[6], pr[7]);
    return pk.v;
  };

  for (int iv = 0; iv < niv; ++iv) {
    __syncthreads();  // drains vmcnt -> interval iv resident in kv[iv&1]
    const int cb = iv & 1;
    const bf16x8* bK = kv[cb];

    // V batch 0 (tile 2iv), issued early; consumed after QK0/softmax0
    bf16x8 av0[8];
    const bf16x8* vg0 =
        (const bf16x8*)(VT + (size_t)(2 * iv) * 8192) + (qd * 128 + c);
#pragma unroll
    for (int dt = 0; dt < 8; ++dt) av0[dt] = vg0[dt * 16];

    bf16x8 pf0 = qkp(bK, 2 * iv);

#pragma unroll
    for (int dt = 0; dt < 8; ++dt)
      o[dt] = __builtin_amdgcn_mfma_f32_16x16x32_bf16(av0[dt], pf0, o[dt], 0, 0, 0);

    // V batch 1 (tile 2iv+1) + next-interval K stage, issued before QK1 so
    // their latency hides under QK1/softmax1
    bf16x8 av1[8];
    const bf16x8* vg1 =
        (const bf16x8*)(VT + (size_t)(2 * iv + 1) * 8192) + (qd * 128 + c);
#pragma unroll
    for (int dt = 0; dt < 8; ++dt) av1[dt] = vg1[dt * 16];

    if (iv + 1 < niv) stage(iv + 1, cb ^ 1);

    bf16x8 pf1 = qkp(bK + 512, 2 * iv + 1);

#pragma unroll
    for (int dt = 0; dt < 8; ++dt)
      o[dt] = __builtin_amdgcn_mfma_f32_16x16x32_bf16(av1[dt], pf1, o[dt], 0, 0, 0);
  }

  // l reduction across the 4 qd lanes of this q-row
  float l = l_part;
  l += __shfl_xor(l, 16);
  l += __shfl_xor(l, 32);
  const float linv = 1.f / l;

  float* orow = Out + ((size_t)(b * SS + qt * 64 + w * 16 + c) * NH + h) * DD;
#pragma unroll
  for (int dt = 0; dt < 8; ++dt) {
    float4 ov;
    ov.x = o[dt][0] * linv; ov.y = o[dt][1] * linv;
    ov.z = o[dt][2] * linv; ov.w = o[dt][3] * linv;
    *(float4*)(orow + dt * 16 + qd * 4) = ov;
  }
  if (qt == 31 && qd == 0)  // persist l for score kernel
    wsl[bh * 64 + w * 16 + c] = l;
}

// ---------------------------------------------------------------------------
// score: grid 1024 (32 k-tile64 x 32 bh). Standard orientation (col=kcol) so
// column sums are reg-sums + 2 shuffles. K frags straight from global Kb.
// ---------------------------------------------------------------------------
__global__ __launch_bounds__(256, 2) void score(
    const float* __restrict__ Q, const short* __restrict__ Kb,
    const float* __restrict__ wsl, float* __restrict__ out2) {
  __shared__ float ldsS[4][64];
  const int tid = threadIdx.x;
  const int w = tid >> 6, lane = tid & 63;
  const int c = lane & 15, qd = lane >> 4;
  const int bh = blockIdx.x & 31, kt = blockIdx.x >> 5;  // kt: 64-col tile 0..31
  const int b = bh >> 4, h = bh & 15, hk = h >> 2;
  const int q0 = SS - 64;

  const float* qrow = Q + ((size_t)(b * SS + q0 + w * 16 + c) * NH + h) * DD;
  bf16x8 qf[4];
#pragma unroll
  for (int ks = 0; ks < 4; ++ks) {
    const float* p = qrow + ks * 32 + qd * 8;
    float4 f0 = *(const float4*)p;
    float4 f1 = *(const float4*)(p + 4);
    bf16x8 t;
    t[0] = f2bf(f0.x * SCL); t[1] = f2bf(f0.y * SCL);
    t[2] = f2bf(f0.z * SCL); t[3] = f2bf(f0.w * SCL);
    t[4] = f2bf(f1.x * SCL); t[5] = f2bf(f1.y * SCL);
    t[6] = f2bf(f1.z * SCL); t[7] = f2bf(f1.w * SCL);
    qf[ks] = t;
  }
  float linv[4];
  const int r0 = bh * 64 + w * 16 + qd * 4;
#pragma unroll
  for (int r = 0; r < 4; ++r) linv[r] = 1.f / wsl[r0 + r];

  const bf16x8* kb = (const bf16x8*)Kb + ((size_t)(b * 4 + hk) * 64 + kt * 2) * 512;
  f32x4 s[4];
#pragma unroll
  for (int nt = 0; nt < 4; ++nt) { s[nt][0] = 0.f; s[nt][1] = 0.f; s[nt][2] = 0.f; s[nt][3] = 0.f; }
#pragma unroll
  for (int ks = 0; ks < 4; ++ks) {
#pragma unroll
    for (int nt = 0; nt < 4; ++nt) {
      bf16x8 kf = kb[(nt >> 1) * 512 + (ks * 4 + qd) * 32 + (nt & 1) * 16 + c];
      s[nt] = __builtin_amdgcn_mfma_f32_16x16x32_bf16(qf[ks], kf, s[nt], 0, 0, 0);
    }
  }
  const bool diag = (kt == 31);
  float cs[4] = {0.f, 0.f, 0.f, 0.f};
#pragma unroll
  for (int nt = 0; nt < 4; ++nt) {
#pragma unroll
    for (int r = 0; r < 4; ++r) {
      float pv = exp2f(s[nt][r]) * linv[r];
      if (diag && nt * 16 + c > w * 16 + qd * 4 + r) pv = 0.f;
      cs[nt] += pv;
    }
    cs[nt] += __shfl_xor(cs[nt], 16);
    cs[nt] += __shfl_xor(cs[nt], 32);
  }
  if (lane < 16) {
#pragma unroll
    for (int nt = 0; nt < 4; ++nt) ldsS[w][nt * 16 + c] = cs[nt];
  }
  __syncthreads();
  if (tid < 64)
    out2[(size_t)bh * SS + kt * 64 + tid] =
        ldsS[0][tid] + ldsS[1][tid] + ldsS[2][tid] + ldsS[3][tid];
}

extern "C" void kernel_launch(void* const* d_in, const int* in_sizes, int n_in,
                              void* d_out, int out_size, void* d_ws, size_t ws_size,
                              hipStream_t stream) {
  const float* Q = (const float*)d_in[0];
  const float* K = (const float*)d_in[1];
  const float* V = (const float*)d_in[2];
  float* out = (float*)d_out;
  float* out2 = out + (size_t)BB * SS * NH * DD;  // [B,H,S] score_sum

  short* Kb = (short*)d_ws;
  const size_t tsz = (size_t)2 * 4 * 64 * TILE_SH;  // 4MB per tensor
  short* Vb = Kb + tsz;
  float* wsl = (float*)(Vb + tsz);

  hipLaunchKernelGGL(prep, dim3(512), dim3(256), 0, stream, K, V, Kb, Vb);
  hipLaunchKernelGGL(fa2, dim3(1024), dim3(256), 0, stream, Q, Kb, Vb, out, wsl);
  hipLaunchKernelGGL(score, dim3(1024), dim3(256), 0, stream, Q, Kb, wsl, out2);
}